// Round 5
// baseline (2319.755 us; speedup 1.0000x reference)
//
#include <hip/hip_runtime.h>

#define HH 128
#define WW 128
#define CIN 64
#define COUT 64
#define NTAP 9

typedef __attribute__((ext_vector_type(8))) short bf16x8;   // 8 bf16 (4 VGPRs)
typedef __attribute__((ext_vector_type(4))) float f32x4;    // MFMA accumulator

#define XB_ROW_US (130 * 64)                    // ushorts per (sample,row) = 16640 B
#define XB_BYTES  ((size_t)8 * 130 * XB_ROW_US * 2)  // 17,305,600 B
#define XB_OFF    81920

__device__ inline ushort f2bf(float f) {
    union { float f; uint u; } v; v.f = f;
    uint u = v.u;
    return (ushort)((u + 0x7FFF + ((u >> 16) & 1)) >> 16);   // RNE
}

// ---------------------------------------------------------------------------
// Prep W: pack weights into MFMA-fragment order, bf16.
// ---------------------------------------------------------------------------
__global__ void prep_w(const float* __restrict__ weight, ushort* __restrict__ wfrag) {
    int idx = blockIdx.x * 256 + threadIdx.x;
    if (idx >= NTAP * 2 * 4 * 64 * 8) return;
    int j  = idx & 7;
    int l  = (idx >> 3) & 63;
    int f  = (idx >> 9) & 3;
    int ks = (idx >> 11) & 1;
    int tp = idx >> 12;
    int co = f * 16 + (l & 15);
    int ci = ks * 32 + (l >> 4) * 8 + j;
    wfrag[idx] = f2bf(weight[((size_t)co * CIN + ci) * NTAP + tp]);
}

// ---------------------------------------------------------------------------
// Prep X: transpose first 8 samples to plain bf16 [i][row -1..128][xs 0..129][ci].
// ---------------------------------------------------------------------------
__global__ __launch_bounds__(256) void prep_x(const float* __restrict__ x,
                                              ushort* __restrict__ xb) {
    __shared__ uint tile[130 * 33];      // [xs][cp], stride 33 dwords
    const int blk = blockIdx.x;          // 0..1039
    const int i = blk / 130;
    const int r = blk % 130;             // xb row; image row = r-1
    uint* dst = (uint*)(xb + (size_t)(i * 130 + r) * XB_ROW_US);  // 4160 uints
    const int ir = r - 1;
    if (ir < 0 || ir >= HH) {
        for (int e = threadIdx.x; e < 4160; e += 256) dst[e] = 0;
        return;
    }
    const float* xrow = x + ((size_t)i * CIN * HH + ir) * WW;
    for (int e = threadIdx.x; e < 32 * 130; e += 256) {
        int cp = e / 130;
        int xs = e - cp * 130;
        uint v = 0;
        if (xs >= 1 && xs <= 128) {
            const float* p = xrow + (size_t)(2 * cp) * HH * WW + (xs - 1);
            v = (uint)f2bf(p[0]) | ((uint)f2bf(p[HH * WW]) << 16);
        }
        tile[xs * 33 + cp] = v;
    }
    __syncthreads();
    for (int e = threadIdx.x; e < 4160; e += 256) {
        int xs = e >> 5, cp = e & 31;
        dst[e] = tile[xs * 33 + cp];
    }
}

// ---------------------------------------------------------------------------
// Kernel 1: dense conv via bf16 MFMA implicit GEMM, NO LDS.
// MEASUREMENT: template REP repeats the whole body (idempotent rewrites);
// asm memory clobber per rep defeats hoisting so each rep redoes loads+MFMA.
// ---------------------------------------------------------------------------
template <int REP>
__global__ __launch_bounds__(256, 3) void conv_first_direct(
    const ushort* __restrict__ xb, const ushort* __restrict__ wfrag,
    const float* __restrict__ bias, float* __restrict__ out)
{
    const int bid = blockIdx.x;
    const int i = bid & 7;                 // sample -> XCD locality
    const int y = bid >> 3;                // output row
    const int t = threadIdx.x;
    const int wv = t >> 6;                 // wave 0..3
    const int l  = t & 63;
    const int g  = l >> 4;                 // k-group
    const int ln = l & 15;
    const int xbase = wv * 32;

    const bf16x8* Wp = (const bf16x8*)wfrag;
    const ushort* Ab = xb + (size_t)(i * 130 + y) * XB_ROW_US;  // rows y..y+2

#pragma unroll 1
    for (int rep = 0; rep < REP; ++rep) {
        asm volatile("" :: "s"(rep) : "memory");   // defeat cross-rep CSE/hoist

        f32x4 acc[4][2];
#pragma unroll
        for (int f = 0; f < 4; ++f)
#pragma unroll
            for (int xfi = 0; xfi < 2; ++xfi)
                acc[f][xfi] = (f32x4){0.f, 0.f, 0.f, 0.f};

#pragma unroll
        for (int tap = 0; tap < NTAP; ++tap) {
            const int kh = tap / 3, kw = tap % 3;
            bf16x8 wf[2][4];
#pragma unroll
            for (int ks = 0; ks < 2; ++ks)
#pragma unroll
                for (int f = 0; f < 4; ++f)
                    wf[ks][f] = Wp[((tap * 2 + ks) * 4 + f) * 64 + l];
            bf16x8 xf_[2][2];
#pragma unroll
            for (int xfi = 0; xfi < 2; ++xfi)
#pragma unroll
                for (int ks = 0; ks < 2; ++ks) {
                    int xs = xbase + xfi * 16 + ln + kw;   // 0..129
                    xf_[xfi][ks] = *(const bf16x8*)(
                        Ab + (size_t)(kh * 130 + xs) * 64 + ks * 32 + g * 8);
                }
#pragma unroll
            for (int f = 0; f < 4; ++f)
#pragma unroll
                for (int xfi = 0; xfi < 2; ++xfi)
#pragma unroll
                    for (int ks = 0; ks < 2; ++ks)
                        acc[f][xfi] = __builtin_amdgcn_mfma_f32_16x16x32_bf16(
                            wf[ks][f], xf_[xfi][ks], acc[f][xfi], 0, 0, 0);
        }

#pragma unroll
        for (int f = 0; f < 4; ++f) {
#pragma unroll
            for (int r = 0; r < 4; ++r) {
                int co = f * 16 + g * 4 + r;
                float b = (i == 0) ? bias[co] : 0.f;
#pragma unroll
                for (int xfi = 0; xfi < 2; ++xfi) {
                    int xcol = xbase + xfi * 16 + ln;
                    out[(((size_t)i * COUT + co) * HH + y) * WW + xcol] = acc[f][xfi][r] + b;
                }
            }
        }
    }
}

// ---------------------------------------------------------------------------
// Kernel 2: per-term single-channel convs. MEASUREMENT: REP repeats; trailing
// barrier per rep prevents rep r+1 staging racing rep r reads.
// ---------------------------------------------------------------------------
constexpr int K2_NCO = 16;

template <int REP>
__global__ __launch_bounds__(256) void conv_terms(
    const float* __restrict__ x, const float* __restrict__ weight,
    const int* __restrict__ term_errors, const int* __restrict__ term_feats,
    float* __restrict__ out, int i_first)
{
    __shared__ float tile[10][132];
    const int t     = blockIdx.y;
    const int strip = blockIdx.x & 15;
    const int cog   = blockIdx.x >> 4;

#pragma unroll 1
    for (int rep = 0; rep < REP; ++rep) {
        asm volatile("" :: "s"(rep) : "memory");   // defeat cross-rep CSE/hoist

        const int e = term_errors[t];
        const int f = term_feats[t];
        const float* xp = x + ((size_t)e * CIN + f) * HH * WW;
        const int y0 = strip * 8;

        for (int idx = threadIdx.x; idx < 10 * 130; idx += 256) {
            int gy = idx / 130, gx = idx % 130;
            int yy = y0 + gy - 1, xx = gx - 1;
            float v = 0.f;
            if (yy >= 0 && yy < HH && xx >= 0 && xx < WW) v = xp[yy * WW + xx];
            tile[gy][gx] = v;
        }
        __syncthreads();

        const int r  = threadIdx.x >> 5;
        const int cq = (threadIdx.x & 31) * 4;

        float xv[3][6];
#pragma unroll
        for (int kh = 0; kh < 3; ++kh)
#pragma unroll
            for (int j = 0; j < 6; ++j)
                xv[kh][j] = tile[r + kh][cq + j];

        const int oy = y0 + r;
#pragma unroll
        for (int c = 0; c < K2_NCO; ++c) {
            int co = cog * K2_NCO + c;
            const float* wc = weight + ((size_t)co * CIN + f) * 9;
            float op[4];
#pragma unroll
            for (int p = 0; p < 4; ++p) {
                float s = 0.f;
#pragma unroll
                for (int kh = 0; kh < 3; ++kh)
#pragma unroll
                    for (int kw = 0; kw < 3; ++kw)
                        s = fmaf(xv[kh][p + kw], wc[kh * 3 + kw], s);
                op[p] = s;
            }
            float4* dst = (float4*)&out[
                ((((size_t)(i_first + t)) * COUT + co) * HH + oy) * WW + cq];
            *dst = make_float4(op[0], op[1], op[2], op[3]);
        }
        __syncthreads();   // protect tile before next rep's staging
    }
}

// ---------------------------------------------------------------------------
// Fallback k1 (round-2 inline-staging kernel) if ws_size too small for xb.
// ---------------------------------------------------------------------------
__global__ __launch_bounds__(256, 3) void conv_first_mfma_fb(
    const float* __restrict__ x, const ushort* __restrict__ wfrag,
    const float* __restrict__ bias, float* __restrict__ out)
{
    __shared__ ushort A[3 * 130 * 64];
    const int wg = (blockIdx.x & 7) * 128 + (blockIdx.x >> 3);
    const int i = wg >> 7;
    const int y = wg & 127;
    const int t = threadIdx.x;
    {
        uint* Az = (uint*)A;
        for (int e = t; e < 6 * 32; e += 256) {
            int rr = e >> 5;
            int kh = rr >> 1;
            int xs = (rr & 1) ? 129 : 0;
            Az[(kh * 130 + xs) * 32 + (e & 31)] = 0;
        }
    }
    const float* xi = x + (size_t)i * CIN * HH * WW;
    for (int it = 0; it < 48; ++it) {
        int flat = it * 256 + t;
        int xs = (flat & 127) + 1;
        int cp = (flat >> 7) & 31;
        int kh = flat >> 12;
        int yy = y + kh - 1;
        uint v = 0;
        if (yy >= 0 && yy < HH) {
            const float* p = xi + ((size_t)(2 * cp) * HH + yy) * WW + (xs - 1);
            v = (uint)f2bf(p[0]) | ((uint)f2bf(p[HH * WW]) << 16);
        }
        int slot = (cp >> 2) ^ (xs & 7);
        ((uint*)A)[(kh * 130 + xs) * 32 + slot * 4 + (cp & 3)] = v;
    }
    __syncthreads();

    const int wv = t >> 6;
    const int l  = t & 63;
    const int g  = l >> 4;
    const int ln = l & 15;
    const int xbase = wv * 32;
    f32x4 acc[4][2];
#pragma unroll
    for (int f = 0; f < 4; ++f)
#pragma unroll
        for (int xfi = 0; xfi < 2; ++xfi)
            acc[f][xfi] = (f32x4){0.f, 0.f, 0.f, 0.f};
    const bf16x8* Wp = (const bf16x8*)wfrag;
#pragma unroll
    for (int tap = 0; tap < NTAP; ++tap) {
        const int kh = tap / 3, kw = tap % 3;
        bf16x8 wf[2][4];
#pragma unroll
        for (int ks = 0; ks < 2; ++ks)
#pragma unroll
            for (int f = 0; f < 4; ++f)
                wf[ks][f] = Wp[((tap * 2 + ks) * 4 + f) * 64 + l];
        bf16x8 xf_[2][2];
#pragma unroll
        for (int xfi = 0; xfi < 2; ++xfi)
#pragma unroll
            for (int ks = 0; ks < 2; ++ks) {
                int xs = xbase + xfi * 16 + ln + kw;
                int slot = (ks * 4 + g) ^ (xs & 7);
                xf_[xfi][ks] = *(const bf16x8*)(A + (size_t)(kh * 130 + xs) * 64 + slot * 8);
            }
#pragma unroll
        for (int f = 0; f < 4; ++f)
#pragma unroll
            for (int xfi = 0; xfi < 2; ++xfi)
#pragma unroll
                for (int ks = 0; ks < 2; ++ks)
                    acc[f][xfi] = __builtin_amdgcn_mfma_f32_16x16x32_bf16(
                        wf[ks][f], xf_[xfi][ks], acc[f][xfi], 0, 0, 0);
    }
#pragma unroll
    for (int f = 0; f < 4; ++f)
#pragma unroll
        for (int r = 0; r < 4; ++r) {
            int co = f * 16 + g * 4 + r;
            float b = (i == 0) ? bias[co] : 0.f;
#pragma unroll
            for (int xfi = 0; xfi < 2; ++xfi) {
                int xcol = xbase + xfi * 16 + ln;
                out[(((size_t)i * COUT + co) * HH + y) * WW + xcol] = acc[f][xfi][r] + b;
            }
        }
}

extern "C" void kernel_launch(void* const* d_in, const int* in_sizes, int n_in,
                              void* d_out, int out_size, void* d_ws, size_t ws_size,
                              hipStream_t stream) {
    const float* x          = (const float*)d_in[0];
    const float* weight     = (const float*)d_in[1];
    const float* bias       = (const float*)d_in[2];
    const int* term_errors  = (const int*)d_in[3];
    const int* term_feats   = (const int*)d_in[4];
    float* out = (float*)d_out;
    ushort* wfrag = (ushort*)d_ws;

    const int T = in_sizes[3];                      // 128
    const int n_out = out_size / (COUT * HH * WW);  // 136
    const int i_first = n_out - T;                  // 8

    prep_w<<<(NTAP * 2 * 4 * 64 * 8 + 255) / 256, 256, 0, stream>>>(weight, wfrag);

    if (ws_size >= XB_OFF + XB_BYTES) {
        ushort* xb = (ushort*)((char*)d_ws + XB_OFF);
        prep_x<<<i_first * 130, 256, 0, stream>>>(x, xb);
        // MEASUREMENT: x32 repeats -> surfaces in rocprof top-5 with counters
        conv_first_direct<32><<<i_first * HH, 256, 0, stream>>>(xb, wfrag, bias, out);
    } else {
        conv_first_mfma_fb<<<i_first * HH, 256, 0, stream>>>(x, wfrag, bias, out);
    }

    dim3 g2(16 * (COUT / K2_NCO), T);
    // MEASUREMENT: x5 repeats -> surfaces in rocprof top-5 with counters
    conv_terms<5><<<g2, 256, 0, stream>>>(x, weight, term_errors, term_feats,
                                          out, i_first);
}

// Round 6
// 173.691 us; speedup vs baseline: 13.3556x; 13.3556x over previous
//
#include <hip/hip_runtime.h>

#define HH 128
#define WW 128
#define CIN 64
#define COUT 64
#define NTAP 9

typedef __attribute__((ext_vector_type(8))) short bf16x8;   // 8 bf16 (4 VGPRs)
typedef __attribute__((ext_vector_type(4))) float f32x4;    // MFMA accumulator

#define XB_ROW_US (130 * 64)                    // ushorts per (sample,row) = 16640 B
#define XB_BYTES  ((size_t)8 * 130 * XB_ROW_US * 2)  // 17,305,600 B
#define XB_OFF    81920
#define WF_HALF_US 18432                        // ushorts per co-half = 36864 B

__device__ inline ushort f2bf(float f) {
    union { float f; uint u; } v; v.f = f;
    uint u = v.u;
    return (ushort)((u + 0x7FFF + ((u >> 16) & 1)) >> 16);   // RNE
}

__device__ inline void gl_lds16(const void* g, void* l) {
    __builtin_amdgcn_global_load_lds(
        (const __attribute__((address_space(1))) unsigned int*)g,
        (__attribute__((address_space(3))) unsigned int*)l, 16, 0, 0);
}

// ---------------------------------------------------------------------------
// wfrag layout (NEW, co-half contiguous):
//   idx = (((f*NTAP + tap)*2 + ks)*64 + l)*8 + j
//   co = f*16 + (l&15); ci = ks*32 + (l>>4)*8 + j
// Half ch covers f in {2ch, 2ch+1} -> contiguous 36864 B.
// ---------------------------------------------------------------------------

// ---------------------------------------------------------------------------
// Kernel A: fused prep.
//   bid < 1040  : prep_x block — transpose sample i=bid&7 (XCD-aligned with k1),
//                 row r=bid>>3, to plain bf16 xb[i][r][xs 0..129][ci].
//   bid >= 1040 : prep_w block — pack weights into wfrag (new layout).
// ---------------------------------------------------------------------------
__global__ __launch_bounds__(256) void prep_all(
    const float* __restrict__ x, const float* __restrict__ weight,
    ushort* __restrict__ xb, ushort* __restrict__ wfrag)
{
    __shared__ uint tile[130 * 33];      // [xs][cp], stride 33 dwords
    const int bid = blockIdx.x;
    if (bid < 1040) {
        const int i = bid & 7;           // sample -> XCD = bid%8 = i
        const int r = bid >> 3;          // xb row; image row = r-1
        uint* dst = (uint*)(xb + (size_t)(i * 130 + r) * XB_ROW_US);  // 4160 uints
        const int ir = r - 1;
        if (ir < 0 || ir >= HH) {
            for (int e = threadIdx.x; e < 4160; e += 256) dst[e] = 0;
            return;
        }
        const float* xrow = x + ((size_t)i * CIN * HH + ir) * WW;
        for (int e = threadIdx.x; e < 32 * 130; e += 256) {
            int cp = e / 130;
            int xs = e - cp * 130;
            uint v = 0;
            if (xs >= 1 && xs <= 128) {
                const float* p = xrow + (size_t)(2 * cp) * HH * WW + (xs - 1);
                v = (uint)f2bf(p[0]) | ((uint)f2bf(p[HH * WW]) << 16);
            }
            tile[xs * 33 + cp] = v;
        }
        __syncthreads();
        for (int e = threadIdx.x; e < 4160; e += 256) {
            int xs = e >> 5, cp = e & 31;
            dst[e] = tile[xs * 33 + cp];
        }
    } else {
        int idx = (bid - 1040) * 256 + threadIdx.x;   // 144 blocks -> 36864
        if (idx < NTAP * 2 * 4 * 64 * 8) {
            int j  = idx & 7;
            int l  = (idx >> 3) & 63;
            int ks = (idx >> 9) & 1;
            int rem = idx >> 10;          // f*9 + tap
            int tp = rem % NTAP;
            int f  = rem / NTAP;
            int co = f * 16 + (l & 15);
            int ci = ks * 32 + (l >> 4) * 8 + j;
            wfrag[idx] = f2bf(weight[((size_t)co * CIN + ci) * NTAP + tp]);
        }
    }
}

// ---------------------------------------------------------------------------
// Kernel 1 v3: dense conv via bf16 MFMA implicit GEMM.
// 2048 blocks: i = bid&7 (XCD), y = (bid>>3)&127, ch = bid>>10 (co half).
// Weights for the half staged ONCE to LDS via linear global_load_lds
// (36864 B, 4 blocks/CU); per tap only 4 independent xf global b128 loads.
// ---------------------------------------------------------------------------
__global__ __launch_bounds__(256, 4) void conv_first_v3(
    const ushort* __restrict__ xb, const ushort* __restrict__ wfrag,
    const float* __restrict__ bias, float* __restrict__ out)
{
    __shared__ __align__(16) ushort wlds[WF_HALF_US];   // 36864 B
    const int bid = blockIdx.x;
    const int i  = bid & 7;                // sample -> XCD locality
    const int y  = (bid >> 3) & 127;       // output row
    const int ch = bid >> 10;              // co half 0/1
    const int t = threadIdx.x;

    // stage weight half linearly: 36864 B = 256 thr x 9 x 16 B
    const char* wsrc = (const char*)(wfrag + (size_t)ch * WF_HALF_US);
#pragma unroll
    for (int it = 0; it < 9; ++it)
        gl_lds16(wsrc + it * 4096 + t * 16, (char*)wlds + it * 4096 + t * 16);
    __syncthreads();

    const int wv = t >> 6;                 // wave 0..3
    const int l  = t & 63;
    const int g  = l >> 4;                 // k-group
    const int ln = l & 15;
    const int xbase = wv * 32;
    const ushort* Ab = xb + (size_t)(i * 130 + y) * XB_ROW_US;  // rows y..y+2

    f32x4 acc[2][2];
#pragma unroll
    for (int fl = 0; fl < 2; ++fl)
#pragma unroll
        for (int xfi = 0; xfi < 2; ++xfi)
            acc[fl][xfi] = (f32x4){0.f, 0.f, 0.f, 0.f};

#pragma unroll
    for (int tap = 0; tap < NTAP; ++tap) {
        const int kh = tap / 3, kw = tap % 3;
        // weight frags from LDS (conflict-free b128)
        bf16x8 wf[2][2];                   // [ks][fl]
#pragma unroll
        for (int fl = 0; fl < 2; ++fl)
#pragma unroll
            for (int ks = 0; ks < 2; ++ks)
                wf[ks][fl] = *(const bf16x8*)(
                    wlds + ((fl * NTAP + tap) * 2 + ks) * 512 + l * 8);
        // x frags: 4 independent global b128 loads (L2-resident xb)
        bf16x8 xf[2][2];                   // [xfi][ks]
#pragma unroll
        for (int xfi = 0; xfi < 2; ++xfi)
#pragma unroll
            for (int ks = 0; ks < 2; ++ks) {
                int xs = xbase + xfi * 16 + ln + kw;   // 0..129
                xf[xfi][ks] = *(const bf16x8*)(
                    Ab + (size_t)(kh * 130 + xs) * 64 + ks * 32 + g * 8);
            }
#pragma unroll
        for (int fl = 0; fl < 2; ++fl)
#pragma unroll
            for (int xfi = 0; xfi < 2; ++xfi)
#pragma unroll
                for (int ks = 0; ks < 2; ++ks)
                    acc[fl][xfi] = __builtin_amdgcn_mfma_f32_16x16x32_bf16(
                        wf[ks][fl], xf[xfi][ks], acc[fl][xfi], 0, 0, 0);
    }

    // D: row = co_local = fl*16 + g*4 + r ; col = x = xbase + xfi*16 + ln
#pragma unroll
    for (int fl = 0; fl < 2; ++fl) {
#pragma unroll
        for (int r = 0; r < 4; ++r) {
            int co = (ch * 2 + fl) * 16 + g * 4 + r;
            float b = (i == 0) ? bias[co] : 0.f;
#pragma unroll
            for (int xfi = 0; xfi < 2; ++xfi) {
                int xcol = xbase + xfi * 16 + ln;
                out[(((size_t)i * COUT + co) * HH + y) * WW + xcol] = acc[fl][xfi][r] + b;
            }
        }
    }
}

// ---------------------------------------------------------------------------
// Kernel 2: per-term single-channel convs — round-2 version (near write floor).
// ---------------------------------------------------------------------------
constexpr int K2_NCO = 16;

__global__ __launch_bounds__(256) void conv_terms(
    const float* __restrict__ x, const float* __restrict__ weight,
    const int* __restrict__ term_errors, const int* __restrict__ term_feats,
    float* __restrict__ out, int i_first)
{
    __shared__ float tile[10][132];
    const int t     = blockIdx.y;
    const int strip = blockIdx.x & 15;
    const int cog   = blockIdx.x >> 4;
    const int e = term_errors[t];
    const int f = term_feats[t];
    const float* xp = x + ((size_t)e * CIN + f) * HH * WW;
    const int y0 = strip * 8;

    for (int idx = threadIdx.x; idx < 10 * 130; idx += 256) {
        int gy = idx / 130, gx = idx % 130;
        int yy = y0 + gy - 1, xx = gx - 1;
        float v = 0.f;
        if (yy >= 0 && yy < HH && xx >= 0 && xx < WW) v = xp[yy * WW + xx];
        tile[gy][gx] = v;
    }
    __syncthreads();

    const int r  = threadIdx.x >> 5;
    const int cq = (threadIdx.x & 31) * 4;

    float xv[3][6];
#pragma unroll
    for (int kh = 0; kh < 3; ++kh)
#pragma unroll
        for (int j = 0; j < 6; ++j)
            xv[kh][j] = tile[r + kh][cq + j];

    const int oy = y0 + r;
#pragma unroll
    for (int c = 0; c < K2_NCO; ++c) {
        int co = cog * K2_NCO + c;
        const float* wc = weight + ((size_t)co * CIN + f) * 9;
        float op[4];
#pragma unroll
        for (int p = 0; p < 4; ++p) {
            float s = 0.f;
#pragma unroll
            for (int kh = 0; kh < 3; ++kh)
#pragma unroll
                for (int kw = 0; kw < 3; ++kw)
                    s = fmaf(xv[kh][p + kw], wc[kh * 3 + kw], s);
            op[p] = s;
        }
        float4* dst = (float4*)&out[
            ((((size_t)(i_first + t)) * COUT + co) * HH + oy) * WW + cq];
        *dst = make_float4(op[0], op[1], op[2], op[3]);
    }
}

// ---------------------------------------------------------------------------
// Fallback path if ws_size too small for xb: standalone prep_w (new layout)
// + round-2-style inline-staging k1.
// ---------------------------------------------------------------------------
__global__ void prep_w_fb(const float* __restrict__ weight, ushort* __restrict__ wfrag) {
    int idx = blockIdx.x * 256 + threadIdx.x;
    if (idx >= NTAP * 2 * 4 * 64 * 8) return;
    int j  = idx & 7;
    int l  = (idx >> 3) & 63;
    int ks = (idx >> 9) & 1;
    int rem = idx >> 10;
    int tp = rem % NTAP;
    int f  = rem / NTAP;
    int co = f * 16 + (l & 15);
    int ci = ks * 32 + (l >> 4) * 8 + j;
    wfrag[idx] = f2bf(weight[((size_t)co * CIN + ci) * NTAP + tp]);
}

__global__ __launch_bounds__(256, 3) void conv_first_mfma_fb(
    const float* __restrict__ x, const ushort* __restrict__ wfrag,
    const float* __restrict__ bias, float* __restrict__ out)
{
    __shared__ ushort A[3 * 130 * 64];
    const int wg = (blockIdx.x & 7) * 128 + (blockIdx.x >> 3);
    const int i = wg >> 7;
    const int y = wg & 127;
    const int t = threadIdx.x;
    {
        uint* Az = (uint*)A;
        for (int e = t; e < 6 * 32; e += 256) {
            int rr = e >> 5;
            int kh = rr >> 1;
            int xs = (rr & 1) ? 129 : 0;
            Az[(kh * 130 + xs) * 32 + (e & 31)] = 0;
        }
    }
    const float* xi = x + (size_t)i * CIN * HH * WW;
    for (int it = 0; it < 48; ++it) {
        int flat = it * 256 + t;
        int xs = (flat & 127) + 1;
        int cp = (flat >> 7) & 31;
        int kh = flat >> 12;
        int yy = y + kh - 1;
        uint v = 0;
        if (yy >= 0 && yy < HH) {
            const float* p = xi + ((size_t)(2 * cp) * HH + yy) * WW + (xs - 1);
            v = (uint)f2bf(p[0]) | ((uint)f2bf(p[HH * WW]) << 16);
        }
        int slot = (cp >> 2) ^ (xs & 7);
        ((uint*)A)[(kh * 130 + xs) * 32 + slot * 4 + (cp & 3)] = v;
    }
    __syncthreads();

    const int wv = t >> 6;
    const int l  = t & 63;
    const int g  = l >> 4;
    const int ln = l & 15;
    const int xbase = wv * 32;
    f32x4 acc[4][2];
#pragma unroll
    for (int f = 0; f < 4; ++f)
#pragma unroll
        for (int xfi = 0; xfi < 2; ++xfi)
            acc[f][xfi] = (f32x4){0.f, 0.f, 0.f, 0.f};
    const bf16x8* Wp = (const bf16x8*)wfrag;
#pragma unroll
    for (int tap = 0; tap < NTAP; ++tap) {
        const int kh = tap / 3, kw = tap % 3;
        bf16x8 wf[2][4];
#pragma unroll
        for (int ks = 0; ks < 2; ++ks)
#pragma unroll
            for (int f = 0; f < 4; ++f)
                wf[ks][f] = Wp[((f * NTAP + tap) * 2 + ks) * 64 + l];
        bf16x8 xf_[2][2];
#pragma unroll
        for (int xfi = 0; xfi < 2; ++xfi)
#pragma unroll
            for (int ks = 0; ks < 2; ++ks) {
                int xs = xbase + xfi * 16 + ln + kw;
                int slot = (ks * 4 + g) ^ (xs & 7);
                xf_[xfi][ks] = *(const bf16x8*)(A + (size_t)(kh * 130 + xs) * 64 + slot * 8);
            }
#pragma unroll
        for (int f = 0; f < 4; ++f)
#pragma unroll
            for (int xfi = 0; xfi < 2; ++xfi)
#pragma unroll
                for (int ks = 0; ks < 2; ++ks)
                    acc[f][xfi] = __builtin_amdgcn_mfma_f32_16x16x32_bf16(
                        wf[ks][f], xf_[xfi][ks], acc[f][xfi], 0, 0, 0);
    }
#pragma unroll
    for (int f = 0; f < 4; ++f)
#pragma unroll
        for (int r = 0; r < 4; ++r) {
            int co = f * 16 + g * 4 + r;
            float b = (i == 0) ? bias[co] : 0.f;
#pragma unroll
            for (int xfi = 0; xfi < 2; ++xfi) {
                int xcol = xbase + xfi * 16 + ln;
                out[(((size_t)i * COUT + co) * HH + y) * WW + xcol] = acc[f][xfi][r] + b;
            }
        }
}

extern "C" void kernel_launch(void* const* d_in, const int* in_sizes, int n_in,
                              void* d_out, int out_size, void* d_ws, size_t ws_size,
                              hipStream_t stream) {
    const float* x          = (const float*)d_in[0];
    const float* weight     = (const float*)d_in[1];
    const float* bias       = (const float*)d_in[2];
    const int* term_errors  = (const int*)d_in[3];
    const int* term_feats   = (const int*)d_in[4];
    float* out = (float*)d_out;
    ushort* wfrag = (ushort*)d_ws;

    const int T = in_sizes[3];                      // 128
    const int n_out = out_size / (COUT * HH * WW);  // 136
    const int i_first = n_out - T;                  // 8

    if (ws_size >= XB_OFF + XB_BYTES) {
        ushort* xb = (ushort*)((char*)d_ws + XB_OFF);
        prep_all<<<1040 + 144, 256, 0, stream>>>(x, weight, xb, wfrag);
        conv_first_v3<<<2 * i_first * HH, 256, 0, stream>>>(xb, wfrag, bias, out);
    } else {
        prep_w_fb<<<(NTAP * 2 * 4 * 64 * 8 + 255) / 256, 256, 0, stream>>>(weight, wfrag);
        conv_first_mfma_fb<<<i_first * HH, 256, 0, stream>>>(x, wfrag, bias, out);
    }

    dim3 g2(16 * (COUT / K2_NCO), T);
    conv_terms<<<g2, 256, 0, stream>>>(x, weight, term_errors, term_feats,
                                       out, i_first);
}

// Round 7
// 170.352 us; speedup vs baseline: 13.6174x; 1.0196x over previous
//
#include <hip/hip_runtime.h>

#define HH 128
#define WW 128
#define CIN 64
#define COUT 64
#define NTAP 9

typedef __attribute__((ext_vector_type(8))) short bf16x8;   // 8 bf16 (4 VGPRs)
typedef __attribute__((ext_vector_type(4))) float f32x4;    // MFMA accumulator

#define XB_ROW_US (130 * 64)                    // ushorts per (sample,row) = 16640 B
#define XB_BYTES  ((size_t)8 * 130 * XB_ROW_US * 2)  // 17,305,600 B
#define XB_OFF    81920

__device__ inline ushort f2bf(float f) {
    union { float f; uint u; } v; v.f = f;
    uint u = v.u;
    return (ushort)((u + 0x7FFF + ((u >> 16) & 1)) >> 16);   // RNE
}

// ---------------------------------------------------------------------------
// wfrag layout (co-half contiguous):
//   frag index (bf16x8 units) = ((f*NTAP + tap)*2 + ks)*64 + l
//   co = f*16 + (l&15); ci = ks*32 + (l>>4)*8 + j
// ---------------------------------------------------------------------------

// ---------------------------------------------------------------------------
// Kernel A: fused prep.
//   bid < 1040  : prep_x — transpose sample i=bid&7 (XCD-aligned with k1),
//                 row r=bid>>3, to plain bf16 xb[i][r][xs 0..129][ci].
//   bid >= 1040 : prep_w — pack weights into wfrag.
// ---------------------------------------------------------------------------
__global__ __launch_bounds__(256) void prep_all(
    const float* __restrict__ x, const float* __restrict__ weight,
    ushort* __restrict__ xb, ushort* __restrict__ wfrag)
{
    __shared__ uint tile[130 * 33];      // [xs][cp], stride 33 dwords
    const int bid = blockIdx.x;
    if (bid < 1040) {
        const int i = bid & 7;           // sample -> XCD = bid%8 = i
        const int r = bid >> 3;          // xb row; image row = r-1
        uint* dst = (uint*)(xb + (size_t)(i * 130 + r) * XB_ROW_US);  // 4160 uints
        const int ir = r - 1;
        if (ir < 0 || ir >= HH) {
            for (int e = threadIdx.x; e < 4160; e += 256) dst[e] = 0;
            return;
        }
        const float* xrow = x + ((size_t)i * CIN * HH + ir) * WW;
        for (int e = threadIdx.x; e < 32 * 130; e += 256) {
            int cp = e / 130;
            int xs = e - cp * 130;
            uint v = 0;
            if (xs >= 1 && xs <= 128) {
                const float* p = xrow + (size_t)(2 * cp) * HH * WW + (xs - 1);
                v = (uint)f2bf(p[0]) | ((uint)f2bf(p[HH * WW]) << 16);
            }
            tile[xs * 33 + cp] = v;
        }
        __syncthreads();
        for (int e = threadIdx.x; e < 4160; e += 256) {
            int xs = e >> 5, cp = e & 31;
            dst[e] = tile[xs * 33 + cp];
        }
    } else {
        int idx = (bid - 1040) * 256 + threadIdx.x;   // 144 blocks -> 36864
        if (idx < NTAP * 2 * 4 * 64 * 8) {
            int j  = idx & 7;
            int l  = (idx >> 3) & 63;
            int ks = (idx >> 9) & 1;
            int rem = idx >> 10;          // f*9 + tap
            int tp = rem % NTAP;
            int f  = rem / NTAP;
            int co = f * 16 + (l & 15);
            int ci = ks * 32 + (l >> 4) * 8 + j;
            wfrag[idx] = f2bf(weight[((size_t)co * CIN + ci) * NTAP + tp]);
        }
    }
}

// ---------------------------------------------------------------------------
// Fused kernel v2: 10240 blocks, 1:4 interleave, uniform small footprint.
//   bid = 5q + r. r==0 -> k1 (LDS-free MFMA direct, 2048 blocks, co-half).
//                 r>0  -> k2 (per-term conv, 8192 blocks, write-bound).
// k1: i = bid&7 = (5q)&7 (sample-per-XCD), m=q>>3, y=m&127, ch=m>>7.
// k2: k2id = 4q + (r-1), bijective over [0,8192).
// ---------------------------------------------------------------------------
constexpr int K2_NCO = 16;

__global__ __launch_bounds__(256, 6) void fused2(
    const float* __restrict__ x, const ushort* __restrict__ xb,
    const ushort* __restrict__ wfrag, const float* __restrict__ weight,
    const float* __restrict__ bias,
    const int* __restrict__ term_errors, const int* __restrict__ term_feats,
    float* __restrict__ out, int i_first)
{
    const int bid = blockIdx.x;
    const int q = bid / 5;
    const int r5 = bid - q * 5;
    const int t = threadIdx.x;

    if (r5 == 0) {
        // ---------------- k1: dense conv, MFMA, no LDS --------------------
        const int i  = bid & 7;            // = (5q)&7, sample -> this XCD
        const int m  = q >> 3;             // 0..255
        const int y  = m & 127;            // output row
        const int ch = m >> 7;             // co half 0/1
        const int wv = t >> 6;
        const int l  = t & 63;
        const int g  = l >> 4;
        const int ln = l & 15;
        const int xbase = wv * 32;

        const bf16x8* Wp = (const bf16x8*)wfrag;
        const ushort* Ab = xb + (size_t)(i * 130 + y) * XB_ROW_US;  // rows y..y+2

        f32x4 acc[2][2];
#pragma unroll
        for (int fl = 0; fl < 2; ++fl)
#pragma unroll
            for (int xfi = 0; xfi < 2; ++xfi)
                acc[fl][xfi] = (f32x4){0.f, 0.f, 0.f, 0.f};

#pragma unroll
        for (int tap = 0; tap < NTAP; ++tap) {
            const int kh = tap / 3, kw = tap % 3;
            bf16x8 wf[2][2];               // [ks][fl]
#pragma unroll
            for (int fl = 0; fl < 2; ++fl)
#pragma unroll
                for (int ks = 0; ks < 2; ++ks)
                    wf[ks][fl] = Wp[(((ch * 2 + fl) * NTAP + tap) * 2 + ks) * 64 + l];
            bf16x8 xf[2][2];               // [xfi][ks]
#pragma unroll
            for (int xfi = 0; xfi < 2; ++xfi)
#pragma unroll
                for (int ks = 0; ks < 2; ++ks) {
                    int xs = xbase + xfi * 16 + ln + kw;   // 0..129
                    xf[xfi][ks] = *(const bf16x8*)(
                        Ab + (size_t)(kh * 130 + xs) * 64 + ks * 32 + g * 8);
                }
#pragma unroll
            for (int fl = 0; fl < 2; ++fl)
#pragma unroll
                for (int xfi = 0; xfi < 2; ++xfi)
#pragma unroll
                    for (int ks = 0; ks < 2; ++ks)
                        acc[fl][xfi] = __builtin_amdgcn_mfma_f32_16x16x32_bf16(
                            wf[ks][fl], xf[xfi][ks], acc[fl][xfi], 0, 0, 0);
        }

#pragma unroll
        for (int fl = 0; fl < 2; ++fl) {
#pragma unroll
            for (int rr = 0; rr < 4; ++rr) {
                int co = (ch * 2 + fl) * 16 + g * 4 + rr;
                float b = (i == 0) ? bias[co] : 0.f;
#pragma unroll
                for (int xfi = 0; xfi < 2; ++xfi) {
                    int xcol = xbase + xfi * 16 + ln;
                    out[(((size_t)i * COUT + co) * HH + y) * WW + xcol] = acc[fl][xfi][rr] + b;
                }
            }
        }
    } else {
        // ---------------- k2: per-term single-channel conv ----------------
        __shared__ float tile[10][132];
        const int k2id  = 4 * q + (r5 - 1);
        const int tt    = k2id >> 6;
        const int sub   = k2id & 63;
        const int strip = sub & 15;
        const int cog   = sub >> 4;
        const int e = term_errors[tt];
        const int f = term_feats[tt];
        const float* xp = x + ((size_t)e * CIN + f) * HH * WW;
        const int y0 = strip * 8;

        for (int idx = t; idx < 10 * 130; idx += 256) {
            int gy = idx / 130, gx = idx - gy * 130;
            int yy = y0 + gy - 1, xx = gx - 1;
            float v = 0.f;
            if (yy >= 0 && yy < HH && xx >= 0 && xx < WW) v = xp[yy * WW + xx];
            tile[gy][gx] = v;
        }
        __syncthreads();

        const int rr = t >> 5;
        const int cq = (t & 31) * 4;
        float xv[3][6];
#pragma unroll
        for (int kh = 0; kh < 3; ++kh)
#pragma unroll
            for (int j = 0; j < 6; ++j)
                xv[kh][j] = tile[rr + kh][cq + j];

        const int oy = y0 + rr;
#pragma unroll
        for (int c = 0; c < K2_NCO; ++c) {
            int co = cog * K2_NCO + c;
            const float* wc = weight + ((size_t)co * CIN + f) * 9;
            float op[4];
#pragma unroll
            for (int p = 0; p < 4; ++p) {
                float s = 0.f;
#pragma unroll
                for (int kh = 0; kh < 3; ++kh)
#pragma unroll
                    for (int kw = 0; kw < 3; ++kw)
                        s = fmaf(xv[kh][p + kw], wc[kh * 3 + kw], s);
                op[p] = s;
            }
            float4* dst = (float4*)&out[
                ((((size_t)(i_first + tt)) * COUT + co) * HH + oy) * WW + cq];
            *dst = make_float4(op[0], op[1], op[2], op[3]);
        }
    }
}

// ---------------------------------------------------------------------------
// Fallback path if ws_size too small for xb (round-6 path, passed).
// ---------------------------------------------------------------------------
__global__ void prep_w_fb(const float* __restrict__ weight, ushort* __restrict__ wfrag) {
    int idx = blockIdx.x * 256 + threadIdx.x;
    if (idx >= NTAP * 2 * 4 * 64 * 8) return;
    int j  = idx & 7;
    int l  = (idx >> 3) & 63;
    int ks = (idx >> 9) & 1;
    int rem = idx >> 10;
    int tp = rem % NTAP;
    int f  = rem / NTAP;
    int co = f * 16 + (l & 15);
    int ci = ks * 32 + (l >> 4) * 8 + j;
    wfrag[idx] = f2bf(weight[((size_t)co * CIN + ci) * NTAP + tp]);
}

__global__ __launch_bounds__(256, 3) void conv_first_mfma_fb(
    const float* __restrict__ x, const ushort* __restrict__ wfrag,
    const float* __restrict__ bias, float* __restrict__ out)
{
    __shared__ ushort A[3 * 130 * 64];
    const int wg = (blockIdx.x & 7) * 128 + (blockIdx.x >> 3);
    const int i = wg >> 7;
    const int y = wg & 127;
    const int t = threadIdx.x;
    {
        uint* Az = (uint*)A;
        for (int e = t; e < 6 * 32; e += 256) {
            int rr = e >> 5;
            int kh = rr >> 1;
            int xs = (rr & 1) ? 129 : 0;
            Az[(kh * 130 + xs) * 32 + (e & 31)] = 0;
        }
    }
    const float* xi = x + (size_t)i * CIN * HH * WW;
    for (int it = 0; it < 48; ++it) {
        int flat = it * 256 + t;
        int xs = (flat & 127) + 1;
        int cp = (flat >> 7) & 31;
        int kh = flat >> 12;
        int yy = y + kh - 1;
        uint v = 0;
        if (yy >= 0 && yy < HH) {
            const float* p = xi + ((size_t)(2 * cp) * HH + yy) * WW + (xs - 1);
            v = (uint)f2bf(p[0]) | ((uint)f2bf(p[HH * WW]) << 16);
        }
        int slot = (cp >> 2) ^ (xs & 7);
        ((uint*)A)[(kh * 130 + xs) * 32 + slot * 4 + (cp & 3)] = v;
    }
    __syncthreads();

    const int wv = t >> 6;
    const int l  = t & 63;
    const int g  = l >> 4;
    const int ln = l & 15;
    const int xbase = wv * 32;
    f32x4 acc[4][2];
#pragma unroll
    for (int f = 0; f < 4; ++f)
#pragma unroll
        for (int xfi = 0; xfi < 2; ++xfi)
            acc[f][xfi] = (f32x4){0.f, 0.f, 0.f, 0.f};
    const bf16x8* Wp = (const bf16x8*)wfrag;
#pragma unroll
    for (int tap = 0; tap < NTAP; ++tap) {
        const int kh = tap / 3, kw = tap % 3;
        bf16x8 wf[2][4];
#pragma unroll
        for (int ks = 0; ks < 2; ++ks)
#pragma unroll
            for (int f = 0; f < 4; ++f)
                wf[ks][f] = Wp[((f * NTAP + tap) * 2 + ks) * 64 + l];
        bf16x8 xf_[2][2];
#pragma unroll
        for (int xfi = 0; xfi < 2; ++xfi)
#pragma unroll
            for (int ks = 0; ks < 2; ++ks) {
                int xs = xbase + xfi * 16 + ln + kw;
                int slot = (ks * 4 + g) ^ (xs & 7);
                xf_[xfi][ks] = *(const bf16x8*)(A + (size_t)(kh * 130 + xs) * 64 + slot * 8);
            }
#pragma unroll
        for (int f = 0; f < 4; ++f)
#pragma unroll
            for (int xfi = 0; xfi < 2; ++xfi)
#pragma unroll
                for (int ks = 0; ks < 2; ++ks)
                    acc[f][xfi] = __builtin_amdgcn_mfma_f32_16x16x32_bf16(
                        wf[ks][f], xf_[xfi][ks], acc[f][xfi], 0, 0, 0);
    }
#pragma unroll
    for (int f = 0; f < 4; ++f)
#pragma unroll
        for (int r = 0; r < 4; ++r) {
            int co = f * 16 + g * 4 + r;
            float b = (i == 0) ? bias[co] : 0.f;
#pragma unroll
            for (int xfi = 0; xfi < 2; ++xfi) {
                int xcol = xbase + xfi * 16 + ln;
                out[(((size_t)i * COUT + co) * HH + y) * WW + xcol] = acc[f][xfi][r] + b;
            }
        }
}

__global__ __launch_bounds__(256) void conv_terms_fb(
    const float* __restrict__ x, const float* __restrict__ weight,
    const int* __restrict__ term_errors, const int* __restrict__ term_feats,
    float* __restrict__ out, int i_first)
{
    __shared__ float tile[10][132];
    const int tt    = blockIdx.y;
    const int strip = blockIdx.x & 15;
    const int cog   = blockIdx.x >> 4;
    const int e = term_errors[tt];
    const int f = term_feats[tt];
    const float* xp = x + ((size_t)e * CIN + f) * HH * WW;
    const int y0 = strip * 8;
    for (int idx = threadIdx.x; idx < 10 * 130; idx += 256) {
        int gy = idx / 130, gx = idx % 130;
        int yy = y0 + gy - 1, xx = gx - 1;
        float v = 0.f;
        if (yy >= 0 && yy < HH && xx >= 0 && xx < WW) v = xp[yy * WW + xx];
        tile[gy][gx] = v;
    }
    __syncthreads();
    const int r  = threadIdx.x >> 5;
    const int cq = (threadIdx.x & 31) * 4;
    float xv[3][6];
#pragma unroll
    for (int kh = 0; kh < 3; ++kh)
#pragma unroll
        for (int j = 0; j < 6; ++j)
            xv[kh][j] = tile[r + kh][cq + j];
    const int oy = y0 + r;
#pragma unroll
    for (int c = 0; c < K2_NCO; ++c) {
        int co = cog * K2_NCO + c;
        const float* wc = weight + ((size_t)co * CIN + f) * 9;
        float op[4];
#pragma unroll
        for (int p = 0; p < 4; ++p) {
            float s = 0.f;
#pragma unroll
            for (int kh = 0; kh < 3; ++kh)
#pragma unroll
                for (int kw = 0; kw < 3; ++kw)
                    s = fmaf(xv[kh][p + kw], wc[kh * 3 + kw], s);
            op[p] = s;
        }
        float4* dst = (float4*)&out[
            ((((size_t)(i_first + tt)) * COUT + co) * HH + oy) * WW + cq];
        *dst = make_float4(op[0], op[1], op[2], op[3]);
    }
}

extern "C" void kernel_launch(void* const* d_in, const int* in_sizes, int n_in,
                              void* d_out, int out_size, void* d_ws, size_t ws_size,
                              hipStream_t stream) {
    const float* x          = (const float*)d_in[0];
    const float* weight     = (const float*)d_in[1];
    const float* bias       = (const float*)d_in[2];
    const int* term_errors  = (const int*)d_in[3];
    const int* term_feats   = (const int*)d_in[4];
    float* out = (float*)d_out;
    ushort* wfrag = (ushort*)d_ws;

    const int T = in_sizes[3];                      // 128
    const int n_out = out_size / (COUT * HH * WW);  // 136
    const int i_first = n_out - T;                  // 8

    if (ws_size >= XB_OFF + XB_BYTES) {
        ushort* xb = (ushort*)((char*)d_ws + XB_OFF);
        prep_all<<<1040 + 144, 256, 0, stream>>>(x, weight, xb, wfrag);
        fused2<<<5 * 2048, 256, 0, stream>>>(x, xb, wfrag, weight, bias,
                                             term_errors, term_feats, out, i_first);
    } else {
        prep_w_fb<<<(NTAP * 2 * 4 * 64 * 8 + 255) / 256, 256, 0, stream>>>(weight, wfrag);
        conv_first_mfma_fb<<<i_first * HH, 256, 0, stream>>>(x, wfrag, bias, out);
        dim3 g2(16 * (COUT / K2_NCO), T);
        conv_terms_fb<<<g2, 256, 0, stream>>>(x, weight, term_errors, term_feats,
                                              out, i_first);
    }
}

// Round 8
// 151.364 us; speedup vs baseline: 15.3256x; 1.1254x over previous
//
#include <hip/hip_runtime.h>

#define HH 128
#define WW 128
#define CIN 64
#define COUT 64
#define NTAP 9

typedef __attribute__((ext_vector_type(8))) short bf16x8;   // 8 bf16 (4 VGPRs)
typedef __attribute__((ext_vector_type(4))) float f32x4;    // MFMA accumulator

#define XB_ROW_US (130 * 64)                    // ushorts per (sample,row) = 16640 B
#define XB_BYTES  ((size_t)8 * 130 * XB_ROW_US * 2)  // 17,305,600 B
#define XB_OFF    81920

__device__ inline ushort f2bf(float f) {
    union { float f; uint u; } v; v.f = f;
    uint u = v.u;
    return (ushort)((u + 0x7FFF + ((u >> 16) & 1)) >> 16);   // RNE
}

__device__ inline void gl_lds16(const void* g, void* l) {
    __builtin_amdgcn_global_load_lds(
        (const __attribute__((address_space(1))) unsigned int*)g,
        (__attribute__((address_space(3))) unsigned int*)l, 16, 0, 0);
}

// ---------------------------------------------------------------------------
// wfrag layout (co-half contiguous):
//   frag index (bf16x8 units) = ((f*NTAP + tap)*2 + ks)*64 + l
//   co = f*16 + (l&15); ci = ks*32 + (l>>4)*8 + j
// xb layout (SWIZZLED, round-2-validated):
//   ushort idx(i, r, xs, ci) = (i*130 + r)*XB_ROW_US + xs*64
//                              + (((ci>>3) ^ (xs&7))*8) + (ci&7)
// ---------------------------------------------------------------------------

// ---------------------------------------------------------------------------
// Kernel A: fused prep.
//   bid < 1040  : prep_x — transpose sample i=bid&7 (XCD-aligned with k1),
//                 row r=bid>>3, to swizzled bf16 xb.
//   bid >= 1040 : prep_w — pack weights into wfrag.
// ---------------------------------------------------------------------------
__global__ __launch_bounds__(256) void prep_all(
    const float* __restrict__ x, const float* __restrict__ weight,
    ushort* __restrict__ xb, ushort* __restrict__ wfrag)
{
    __shared__ uint tile[130 * 33];      // [xs][cp], stride 33 dwords
    const int bid = blockIdx.x;
    if (bid < 1040) {
        const int i = bid & 7;           // sample -> XCD = bid%8 = i
        const int r = bid >> 3;          // xb row; image row = r-1
        uint* dst = (uint*)(xb + (size_t)(i * 130 + r) * XB_ROW_US);  // 4160 uints
        const int ir = r - 1;
        if (ir < 0 || ir >= HH) {
            for (int e = threadIdx.x; e < 4160; e += 256) dst[e] = 0;
            return;
        }
        const float* xrow = x + ((size_t)i * CIN * HH + ir) * WW;
        for (int e = threadIdx.x; e < 32 * 130; e += 256) {
            int cp = e / 130;
            int xs = e - cp * 130;
            uint v = 0;
            if (xs >= 1 && xs <= 128) {
                const float* p = xrow + (size_t)(2 * cp) * HH * WW + (xs - 1);
                v = (uint)f2bf(p[0]) | ((uint)f2bf(p[HH * WW]) << 16);
            }
            tile[xs * 33 + cp] = v;
        }
        __syncthreads();
        // swizzled write-out: uint idx = xs*32 + ((cp>>2)^(xs&7))*4 + (cp&3)
        for (int e = threadIdx.x; e < 4160; e += 256) {
            int xs = e >> 5, cp = e & 31;
            dst[xs * 32 + ((cp >> 2) ^ (xs & 7)) * 4 + (cp & 3)] = tile[xs * 33 + cp];
        }
    } else {
        int idx = (bid - 1040) * 256 + threadIdx.x;   // 144 blocks -> 36864
        if (idx < NTAP * 2 * 4 * 64 * 8) {
            int j  = idx & 7;
            int l  = (idx >> 3) & 63;
            int ks = (idx >> 9) & 1;
            int rem = idx >> 10;          // f*9 + tap
            int tp = rem % NTAP;
            int f  = rem / NTAP;
            int co = f * 16 + (l & 15);
            int ci = ks * 32 + (l >> 4) * 8 + j;
            wfrag[idx] = f2bf(weight[((size_t)co * CIN + ci) * NTAP + tp]);
        }
    }
}

// ---------------------------------------------------------------------------
// Kernel 1 v4: dense conv via bf16 MFMA. Each block: 2 output rows x 64 co
// x 128 x for one sample. 512 blocks: i=bid&7 (XCD), y0=(bid>>3)*2.
// 4 waves: rl=wv&1 (row), ch=wv>>1 (co half). LDS: 4 swizzled xb rows
// (66560 B) staged once via linear global_load_lds -> re-read factor 2
// (was 6), ds_read_b128 ~2-way max. Weights from L2-resident wfrag.
// ---------------------------------------------------------------------------
__global__ __launch_bounds__(256, 2) void conv_first_v4(
    const ushort* __restrict__ xb, const ushort* __restrict__ wfrag,
    const float* __restrict__ bias, float* __restrict__ out)
{
    __shared__ __align__(16) ushort A[4 * 130 * 64];   // 66560 B
    const int bid = blockIdx.x;
    const int i  = bid & 7;                // sample -> XCD locality
    const int y0 = (bid >> 3) * 2;         // 0..126
    const int t = threadIdx.x;

    // stage xb rows y0..y0+3 (image rows y0-1..y0+2), 66560 B linear
    const char* src = (const char*)(xb + (size_t)(i * 130 + y0) * XB_ROW_US);
#pragma unroll
    for (int it = 0; it < 16; ++it)
        gl_lds16(src + it * 4096 + t * 16, (char*)A + it * 4096 + t * 16);
    if (t < 64)
        gl_lds16(src + 65536 + t * 16, (char*)A + 65536 + t * 16);
    __syncthreads();

    const int wv = t >> 6;
    const int rl = wv & 1;                 // row within pair
    const int ch = wv >> 1;                // co half
    const int l  = t & 63;
    const int g  = l >> 4;                 // k-group
    const int ln = l & 15;
    const int y  = y0 + rl;

    f32x4 acc[2][8];                       // [fl][xfi]
#pragma unroll
    for (int fl = 0; fl < 2; ++fl)
#pragma unroll
        for (int xfi = 0; xfi < 8; ++xfi)
            acc[fl][xfi] = (f32x4){0.f, 0.f, 0.f, 0.f};

    const bf16x8* Wp = (const bf16x8*)wfrag;

#pragma unroll
    for (int tap = 0; tap < NTAP; ++tap) {
        const int kh = tap / 3, kw = tap % 3;
        bf16x8 wf[2][2];                   // [ks][fl], L2-resident global
#pragma unroll
        for (int fl = 0; fl < 2; ++fl)
#pragma unroll
            for (int ks = 0; ks < 2; ++ks)
                wf[ks][fl] = Wp[(((ch * 2 + fl) * NTAP + tap) * 2 + ks) * 64 + l];
#pragma unroll
        for (int xfi = 0; xfi < 8; ++xfi) {
            bf16x8 xf[2];
#pragma unroll
            for (int ks = 0; ks < 2; ++ks) {
                int xs = xfi * 16 + ln + kw;           // 0..129
                int slot = (ks * 4 + g) ^ (xs & 7);
                xf[ks] = *(const bf16x8*)(
                    A + (size_t)((rl + kh) * 130 + xs) * 64 + slot * 8);
            }
#pragma unroll
            for (int fl = 0; fl < 2; ++fl)
#pragma unroll
                for (int ks = 0; ks < 2; ++ks)
                    acc[fl][xfi] = __builtin_amdgcn_mfma_f32_16x16x32_bf16(
                        wf[ks][fl], xf[ks], acc[fl][xfi], 0, 0, 0);
        }
    }

    // D: co = ch*32 + fl*16 + g*4 + rr ; col = x = xfi*16 + ln
#pragma unroll
    for (int fl = 0; fl < 2; ++fl) {
#pragma unroll
        for (int rr = 0; rr < 4; ++rr) {
            int co = ch * 32 + fl * 16 + g * 4 + rr;
            float b = (i == 0) ? bias[co] : 0.f;
#pragma unroll
            for (int xfi = 0; xfi < 8; ++xfi) {
                int xcol = xfi * 16 + ln;
                out[(((size_t)i * COUT + co) * HH + y) * WW + xcol] = acc[fl][xfi][rr] + b;
            }
        }
    }
}

// ---------------------------------------------------------------------------
// Kernel 2: per-term single-channel convs — round-2 version (near write floor).
// ---------------------------------------------------------------------------
constexpr int K2_NCO = 16;

__global__ __launch_bounds__(256) void conv_terms(
    const float* __restrict__ x, const float* __restrict__ weight,
    const int* __restrict__ term_errors, const int* __restrict__ term_feats,
    float* __restrict__ out, int i_first)
{
    __shared__ float tile[10][132];
    const int t     = blockIdx.y;
    const int strip = blockIdx.x & 15;
    const int cog   = blockIdx.x >> 4;
    const int e = term_errors[t];
    const int f = term_feats[t];
    const float* xp = x + ((size_t)e * CIN + f) * HH * WW;
    const int y0 = strip * 8;

    for (int idx = threadIdx.x; idx < 10 * 130; idx += 256) {
        int gy = idx / 130, gx = idx % 130;
        int yy = y0 + gy - 1, xx = gx - 1;
        float v = 0.f;
        if (yy >= 0 && yy < HH && xx >= 0 && xx < WW) v = xp[yy * WW + xx];
        tile[gy][gx] = v;
    }
    __syncthreads();

    const int r  = threadIdx.x >> 5;
    const int cq = (threadIdx.x & 31) * 4;

    float xv[3][6];
#pragma unroll
    for (int kh = 0; kh < 3; ++kh)
#pragma unroll
        for (int j = 0; j < 6; ++j)
            xv[kh][j] = tile[r + kh][cq + j];

    const int oy = y0 + r;
#pragma unroll
    for (int c = 0; c < K2_NCO; ++c) {
        int co = cog * K2_NCO + c;
        const float* wc = weight + ((size_t)co * CIN + f) * 9;
        float op[4];
#pragma unroll
        for (int p = 0; p < 4; ++p) {
            float s = 0.f;
#pragma unroll
            for (int kh = 0; kh < 3; ++kh)
#pragma unroll
                for (int kw = 0; kw < 3; ++kw)
                    s = fmaf(xv[kh][p + kw], wc[kh * 3 + kw], s);
            op[p] = s;
        }
        float4* dst = (float4*)&out[
            ((((size_t)(i_first + t)) * COUT + co) * HH + oy) * WW + cq];
        *dst = make_float4(op[0], op[1], op[2], op[3]);
    }
}

// ---------------------------------------------------------------------------
// Fallback path if ws_size too small for xb.
// ---------------------------------------------------------------------------
__global__ void prep_w_fb(const float* __restrict__ weight, ushort* __restrict__ wfrag) {
    int idx = blockIdx.x * 256 + threadIdx.x;
    if (idx >= NTAP * 2 * 4 * 64 * 8) return;
    int j  = idx & 7;
    int l  = (idx >> 3) & 63;
    int ks = (idx >> 9) & 1;
    int rem = idx >> 10;
    int tp = rem % NTAP;
    int f  = rem / NTAP;
    int co = f * 16 + (l & 15);
    int ci = ks * 32 + (l >> 4) * 8 + j;
    wfrag[idx] = f2bf(weight[((size_t)co * CIN + ci) * NTAP + tp]);
}

__global__ __launch_bounds__(256, 3) void conv_first_mfma_fb(
    const float* __restrict__ x, const ushort* __restrict__ wfrag,
    const float* __restrict__ bias, float* __restrict__ out)
{
    __shared__ ushort A[3 * 130 * 64];
    const int wg = (blockIdx.x & 7) * 128 + (blockIdx.x >> 3);
    const int i = wg >> 7;
    const int y = wg & 127;
    const int t = threadIdx.x;
    {
        uint* Az = (uint*)A;
        for (int e = t; e < 6 * 32; e += 256) {
            int rr = e >> 5;
            int kh = rr >> 1;
            int xs = (rr & 1) ? 129 : 0;
            Az[(kh * 130 + xs) * 32 + (e & 31)] = 0;
        }
    }
    const float* xi = x + (size_t)i * CIN * HH * WW;
    for (int it = 0; it < 48; ++it) {
        int flat = it * 256 + t;
        int xs = (flat & 127) + 1;
        int cp = (flat >> 7) & 31;
        int kh = flat >> 12;
        int yy = y + kh - 1;
        uint v = 0;
        if (yy >= 0 && yy < HH) {
            const float* p = xi + ((size_t)(2 * cp) * HH + yy) * WW + (xs - 1);
            v = (uint)f2bf(p[0]) | ((uint)f2bf(p[HH * WW]) << 16);
        }
        int slot = (cp >> 2) ^ (xs & 7);
        ((uint*)A)[(kh * 130 + xs) * 32 + slot * 4 + (cp & 3)] = v;
    }
    __syncthreads();

    const int wv = t >> 6;
    const int l  = t & 63;
    const int g  = l >> 4;
    const int ln = l & 15;
    const int xbase = wv * 32;
    f32x4 acc[4][2];
#pragma unroll
    for (int f = 0; f < 4; ++f)
#pragma unroll
        for (int xfi = 0; xfi < 2; ++xfi)
            acc[f][xfi] = (f32x4){0.f, 0.f, 0.f, 0.f};
    const bf16x8* Wp = (const bf16x8*)wfrag;
#pragma unroll
    for (int tap = 0; tap < NTAP; ++tap) {
        const int kh = tap / 3, kw = tap % 3;
        bf16x8 wf[2][4];
#pragma unroll
        for (int ks = 0; ks < 2; ++ks)
#pragma unroll
            for (int f = 0; f < 4; ++f)
                wf[ks][f] = Wp[((f * NTAP + tap) * 2 + ks) * 64 + l];
        bf16x8 xf_[2][2];
#pragma unroll
        for (int xfi = 0; xfi < 2; ++xfi)
#pragma unroll
            for (int ks = 0; ks < 2; ++ks) {
                int xs = xbase + xfi * 16 + ln + kw;
                int slot = (ks * 4 + g) ^ (xs & 7);
                xf_[xfi][ks] = *(const bf16x8*)(A + (size_t)(kh * 130 + xs) * 64 + slot * 8);
            }
#pragma unroll
        for (int f = 0; f < 4; ++f)
#pragma unroll
            for (int xfi = 0; xfi < 2; ++xfi)
#pragma unroll
                for (int ks = 0; ks < 2; ++ks)
                    acc[f][xfi] = __builtin_amdgcn_mfma_f32_16x16x32_bf16(
                        wf[ks][f], xf_[xfi][ks], acc[f][xfi], 0, 0, 0);
    }
#pragma unroll
    for (int f = 0; f < 4; ++f)
#pragma unroll
        for (int r = 0; r < 4; ++r) {
            int co = f * 16 + g * 4 + r;
            float b = (i == 0) ? bias[co] : 0.f;
#pragma unroll
            for (int xfi = 0; xfi < 2; ++xfi) {
                int xcol = xbase + xfi * 16 + ln;
                out[(((size_t)i * COUT + co) * HH + y) * WW + xcol] = acc[f][xfi][r] + b;
            }
        }
}

extern "C" void kernel_launch(void* const* d_in, const int* in_sizes, int n_in,
                              void* d_out, int out_size, void* d_ws, size_t ws_size,
                              hipStream_t stream) {
    const float* x          = (const float*)d_in[0];
    const float* weight     = (const float*)d_in[1];
    const float* bias       = (const float*)d_in[2];
    const int* term_errors  = (const int*)d_in[3];
    const int* term_feats   = (const int*)d_in[4];
    float* out = (float*)d_out;
    ushort* wfrag = (ushort*)d_ws;

    const int T = in_sizes[3];                      // 128
    const int n_out = out_size / (COUT * HH * WW);  // 136
    const int i_first = n_out - T;                  // 8

    if (ws_size >= XB_OFF + XB_BYTES) {
        ushort* xb = (ushort*)((char*)d_ws + XB_OFF);
        prep_all<<<1040 + 144, 256, 0, stream>>>(x, weight, xb, wfrag);
        conv_first_v4<<<512, 256, 0, stream>>>(xb, wfrag, bias, out);
    } else {
        prep_w_fb<<<(NTAP * 2 * 4 * 64 * 8 + 255) / 256, 256, 0, stream>>>(weight, wfrag);
        conv_first_mfma_fb<<<i_first * HH, 256, 0, stream>>>(x, wfrag, bias, out);
    }

    dim3 g2(16 * (COUT / K2_NCO), T);
    conv_terms<<<g2, 256, 0, stream>>>(x, weight, term_errors, term_feats,
                                       out, i_first);
}